// Round 3
// baseline (296.489 us; speedup 1.0000x reference)
//
#include <hip/hip_runtime.h>
#include <hip/hip_bf16.h>

#define B_ 4
#define Q_ 64
#define C_ 384
#define H_ 6
#define L_ 5
#define P_ 4
#define DFF_ 1024
#define EXTRA_ 128
#define DH_ 64
#define S_ 66836

#define FLAG_RELU 1
#define FLAG_RES 2

__device__ __forceinline__ float wave_sum(float v) {
    for (int off = 32; off; off >>= 1) v += __shfl_xor(v, off);
    return v;
}
__device__ __forceinline__ float wave_max(float v) {
    for (int off = 32; off; off >>= 1) v = fmaxf(v, __shfl_xor(v, off));
    return v;
}

// ---------- 16-row-tiled linear: out[r,j] = bias[j] + in[r,:].W[j,:] (+res, relu) ----------
// grid: (OUT/64, N/16), block 256, dynamic LDS = 16*K*4 bytes
__global__ __launch_bounds__(256) void lin16_kernel(
        const float* __restrict__ in, const float* __restrict__ W,
        const float* __restrict__ bias, const float* __restrict__ res,
        float* __restrict__ out, int K, int OUT, int flags) {
    extern __shared__ float xs[];
    int t = threadIdx.x;
    int r0 = blockIdx.y * 16;
    int K4 = K >> 2;
    const float4* in4 = reinterpret_cast<const float4*>(in + (size_t)r0 * K);
    float4* xs4 = reinterpret_cast<float4*>(xs);
    for (int i = t; i < 16 * K4; i += 256) xs4[i] = in4[i];
    __syncthreads();
    int j = blockIdx.x * 64 + (t & 63);
    int rg = t >> 6;  // 0..3 -> rows rg*4 .. rg*4+3
    if (j >= OUT) return;
    const float4* wp = reinterpret_cast<const float4*>(W + (size_t)j * K);
    const float4* x0 = reinterpret_cast<const float4*>(xs + (rg * 4 + 0) * K);
    const float4* x1 = reinterpret_cast<const float4*>(xs + (rg * 4 + 1) * K);
    const float4* x2 = reinterpret_cast<const float4*>(xs + (rg * 4 + 2) * K);
    const float4* x3 = reinterpret_cast<const float4*>(xs + (rg * 4 + 3) * K);
    float a0 = 0.f, a1 = 0.f, a2 = 0.f, a3 = 0.f;
#pragma unroll 4
    for (int k = 0; k < K4; ++k) {
        float4 w = wp[k];
        float4 v0 = x0[k], v1 = x1[k], v2 = x2[k], v3 = x3[k];
        a0 += w.x * v0.x + w.y * v0.y + w.z * v0.z + w.w * v0.w;
        a1 += w.x * v1.x + w.y * v1.y + w.z * v1.z + w.w * v1.w;
        a2 += w.x * v2.x + w.y * v2.y + w.z * v2.z + w.w * v2.w;
        a3 += w.x * v3.x + w.y * v3.y + w.z * v3.z + w.w * v3.w;
    }
    float bb = bias[j];
    float v[4] = {a0 + bb, a1 + bb, a2 + bb, a3 + bb};
    int orow = r0 + rg * 4;
#pragma unroll
    for (int i = 0; i < 4; ++i) {
        float o = v[i];
        if (flags & FLAG_RES) o += res[(size_t)(orow + i) * OUT + j];
        if (flags & FLAG_RELU) o = fmaxf(o, 0.f);
        out[(size_t)(orow + i) * OUT + j] = o;
    }
}

// ---------- dual-weight prep: offsets (240) + attn logits (120) from same input ----------
// grid: (6, 16), block 256, dynamic LDS = 16*384*4
__global__ __launch_bounds__(256) void prep_kernel(
        const float* __restrict__ in, const float* __restrict__ Woff,
        const float* __restrict__ boff, const float* __restrict__ Wa,
        const float* __restrict__ ba, float* __restrict__ offs,
        float* __restrict__ lg) {
    extern __shared__ float xs[];
    int t = threadIdx.x;
    int r0 = blockIdx.y * 16;
    const float4* in4 = reinterpret_cast<const float4*>(in + (size_t)r0 * 384);
    float4* xs4 = reinterpret_cast<float4*>(xs);
    for (int i = t; i < 16 * 96; i += 256) xs4[i] = in4[i];
    __syncthreads();
    int j = blockIdx.x * 64 + (t & 63);
    int rg = t >> 6;
    if (j >= 360) return;
    const float4* wp;
    float bb;
    if (j < 240) { wp = reinterpret_cast<const float4*>(Woff + (size_t)j * 384); bb = boff[j]; }
    else         { wp = reinterpret_cast<const float4*>(Wa + (size_t)(j - 240) * 384); bb = ba[j - 240]; }
    const float4* x0 = reinterpret_cast<const float4*>(xs + (rg * 4 + 0) * 384);
    const float4* x1 = reinterpret_cast<const float4*>(xs + (rg * 4 + 1) * 384);
    const float4* x2 = reinterpret_cast<const float4*>(xs + (rg * 4 + 2) * 384);
    const float4* x3 = reinterpret_cast<const float4*>(xs + (rg * 4 + 3) * 384);
    float a0 = 0.f, a1 = 0.f, a2 = 0.f, a3 = 0.f;
#pragma unroll 4
    for (int k = 0; k < 96; ++k) {
        float4 w = wp[k];
        float4 v0 = x0[k], v1 = x1[k], v2 = x2[k], v3 = x3[k];
        a0 += w.x * v0.x + w.y * v0.y + w.z * v0.z + w.w * v0.w;
        a1 += w.x * v1.x + w.y * v1.y + w.z * v1.z + w.w * v1.w;
        a2 += w.x * v2.x + w.y * v2.y + w.z * v2.z + w.w * v2.w;
        a3 += w.x * v3.x + w.y * v3.y + w.z * v3.z + w.w * v3.w;
    }
    float v[4] = {a0 + bb, a1 + bb, a2 + bb, a3 + bb};
    int orow = r0 + rg * 4;
#pragma unroll
    for (int i = 0; i < 4; ++i) {
        if (j < 240) offs[(size_t)(orow + i) * 240 + j] = v[i];
        else         lg[(size_t)(orow + i) * 120 + (j - 240)] = v[i];
    }
}

// ---------- self attention (64 keys), one block per row ----------
__global__ __launch_bounds__(384) void sa_attn_kernel(const float* __restrict__ qkv,
                                                      float* __restrict__ o) {
    int row = blockIdx.x;
    int b = row >> 6;
    int t = threadIdx.x;
    int h = t >> 6, lane = t & 63;
    __shared__ float q_lds[384], a_lds[384];
    q_lds[t] = qkv[(size_t)row * 1152 + t];
    __syncthreads();
    const float* krow = qkv + (size_t)(b * 64 + lane) * 1152 + 384 + h * 64;
    float s = 0.f;
#pragma unroll 8
    for (int d = 0; d < 64; ++d) s += q_lds[h * 64 + d] * krow[d];
    s *= 0.125f;
    float m = wave_max(s);
    float e = __expf(s - m);
    float sum = wave_sum(e);
    a_lds[t] = e / sum;
    __syncthreads();
    float acc = 0.f;
#pragma unroll 4
    for (int k = 0; k < 64; ++k)
        acc += a_lds[h * 64 + k] * qkv[(size_t)(b * 64 + k) * 1152 + 768 + h * 64 + lane];
    o[(size_t)row * 384 + t] = acc;
}

// ---------- cross attention (128 keys), one block per row ----------
__global__ __launch_bounds__(384) void ea_attn_kernel(const float* __restrict__ q,
                                                      const float* __restrict__ kv,
                                                      float* __restrict__ o) {
    int row = blockIdx.x;
    int b = row >> 6;
    int t = threadIdx.x;
    int h = t >> 6, lane = t & 63;
    __shared__ float q_lds[384], a_lds[768];
    q_lds[t] = q[(size_t)row * 384 + t];
    __syncthreads();
    const float* k0 = kv + (size_t)(b * 128 + lane) * 768 + h * 64;
    const float* k1 = k0 + (size_t)64 * 768;
    float s0 = 0.f, s1 = 0.f;
#pragma unroll 8
    for (int d = 0; d < 64; ++d) { float qd = q_lds[h * 64 + d]; s0 += qd * k0[d]; s1 += qd * k1[d]; }
    s0 *= 0.125f; s1 *= 0.125f;
    float m = wave_max(fmaxf(s0, s1));
    float e0 = __expf(s0 - m), e1 = __expf(s1 - m);
    float sum = wave_sum(e0 + e1);
    a_lds[h * 128 + lane] = e0 / sum;
    a_lds[h * 128 + 64 + lane] = e1 / sum;
    __syncthreads();
    float acc = 0.f;
#pragma unroll 4
    for (int k = 0; k < 128; ++k)
        acc += a_lds[h * 128 + k] * kv[(size_t)(b * 128 + k) * 768 + 384 + h * 64 + lane];
    o[(size_t)row * 384 + t] = acc;
}

// ---------- LayerNorm (input already has residual added), one wave per row ----------
__global__ __launch_bounds__(64) void ln_kernel(const float* __restrict__ z,
                                                const float* __restrict__ g,
                                                const float* __restrict__ beta,
                                                float* __restrict__ out) {
    int row = blockIdx.x;
    int t = threadIdx.x;
    float v[6];
    float mean = 0.f;
#pragma unroll
    for (int i = 0; i < 6; ++i) {
        v[i] = z[(size_t)row * C_ + t + i * 64];
        mean += v[i];
    }
    mean = wave_sum(mean) * (1.f / C_);
    float var = 0.f;
#pragma unroll
    for (int i = 0; i < 6; ++i) { float d = v[i] - mean; var += d * d; }
    var = wave_sum(var) * (1.f / C_);
    float inv = rsqrtf(var + 1e-5f);
#pragma unroll
    for (int i = 0; i < 6; ++i) {
        int c = t + i * 64;
        out[(size_t)row * C_ + c] = (v[i] - mean) * inv * g[c] + beta[c];
    }
}

// ---------- deformable gather with local softmax; block per (l,h,row) ----------
__global__ __launch_bounds__(128) void ms_gather_kernel(
        const float* __restrict__ src, const float* __restrict__ refp,
        const float* __restrict__ vr, const float* __restrict__ offs,
        const float* __restrict__ lg, float* __restrict__ pagg,
        float* __restrict__ pwsum) {
    int l = blockIdx.x, h = blockIdx.y, row = blockIdx.z;
    int b = row >> 6;
    int t = threadIdx.x;  // 0..127
    const int lsi[5] = {0, 196, 980, 4116, 16660};
    const int whl[5] = {14, 28, 56, 112, 224};
    int wh = whl[l];
    float Wf = (float)wh;
    // local softmax over the 20 logits of (row,h)
    const float* lp = lg + (size_t)row * 120 + h * 20;
    float m = -1e30f;
#pragma unroll
    for (int k = 0; k < 20; ++k) m = fmaxf(m, lp[k]);
    float denom = 0.f;
#pragma unroll
    for (int k = 0; k < 20; ++k) denom += __expf(lp[k] - m);
    float dinv = 1.f / denom;
    float rpx = refp[row * 2 + 0] * vr[(b * 5 + l) * 2 + 0];
    float rpy = refp[row * 2 + 1] * vr[(b * 5 + l) * 2 + 1];
    const float* srcb = src + ((size_t)b * S_ + lsi[l]) * 384;
    float acc0 = 0.f, acc1 = 0.f, acc2 = 0.f, wsm = 0.f;
#pragma unroll
    for (int p = 0; p < 4; ++p) {
        int oidx = row * 240 + ((h * 5 + l) * 4 + p) * 2;
        float ox = offs[oidx], oy = offs[oidx + 1];
        float x = (rpx + ox / Wf) * Wf - 0.5f;
        float y = (rpy + oy / Wf) * Wf - 0.5f;
        float x0 = floorf(x), y0 = floorf(y);
        float wx = x - x0, wy = y - y0;
        float a = __expf(lp[l * 4 + p] - m) * dinv;
        float cw[4] = {(1.f - wx) * (1.f - wy), wx * (1.f - wy), (1.f - wx) * wy, wx * wy};
        float cx[4] = {x0, x0 + 1.f, x0, x0 + 1.f};
        float cy[4] = {y0, y0, y0 + 1.f, y0 + 1.f};
#pragma unroll
        for (int c2 = 0; c2 < 4; ++c2) {
            bool valid = (cx[c2] >= 0.f) && (cx[c2] <= Wf - 1.f) &&
                         (cy[c2] >= 0.f) && (cy[c2] <= Wf - 1.f);
            if (!valid) continue;  // block-uniform
            float w = a * cw[c2];
            wsm += w;
            int xi = (int)cx[c2], yi = (int)cy[c2];
            const float* sp = srcb + (size_t)(yi * wh + xi) * 384;
            acc0 += w * sp[t];
            acc1 += w * sp[t + 128];
            acc2 += w * sp[t + 256];
        }
    }
    float* ap = pagg + ((size_t)(row * 6 + h) * 5 + l) * 384;
    ap[t] = acc0; ap[t + 128] = acc1; ap[t + 256] = acc2;
    if (t == 0) pwsum[(row * 6 + h) * 5 + l] = wsm;
}

// ---------- level-reduce + value projection; grid (6 heads, 16 row-tiles) ----------
__global__ __launch_bounds__(256) void valproj_kernel(
        const float* __restrict__ pagg, const float* __restrict__ pwsum,
        const float* __restrict__ Wv, const float* __restrict__ bv,
        float* __restrict__ val) {
    __shared__ float xs[16 * 384];
    __shared__ float ws16[16];
    int t = threadIdx.x;
    int h = blockIdx.x;
    int r0 = blockIdx.y * 16;
    float4* xs4 = reinterpret_cast<float4*>(xs);
    for (int i = t; i < 16 * 96; i += 256) {
        int row = i / 96, c4 = i % 96;
        const float4* pp = reinterpret_cast<const float4*>(pagg) +
                           ((size_t)((r0 + row) * 6 + h) * 5) * 96 + c4;
        float4 s = pp[0];
        float4 p1 = pp[96], p2 = pp[192], p3 = pp[288], p4 = pp[384];
        s.x += p1.x + p2.x + p3.x + p4.x;
        s.y += p1.y + p2.y + p3.y + p4.y;
        s.z += p1.z + p2.z + p3.z + p4.z;
        s.w += p1.w + p2.w + p3.w + p4.w;
        xs4[i] = s;
    }
    if (t < 16) {
        const float* pw = pwsum + ((size_t)(r0 + t) * 6 + h) * 5;
        ws16[t] = pw[0] + pw[1] + pw[2] + pw[3] + pw[4];
    }
    __syncthreads();
    int j = h * 64 + (t & 63);
    int rg = t >> 6;
    const float4* wp = reinterpret_cast<const float4*>(Wv + (size_t)j * 384);
    const float4* x0 = reinterpret_cast<const float4*>(xs + (rg * 4 + 0) * 384);
    const float4* x1 = reinterpret_cast<const float4*>(xs + (rg * 4 + 1) * 384);
    const float4* x2 = reinterpret_cast<const float4*>(xs + (rg * 4 + 2) * 384);
    const float4* x3 = reinterpret_cast<const float4*>(xs + (rg * 4 + 3) * 384);
    float a0 = 0.f, a1 = 0.f, a2 = 0.f, a3 = 0.f;
#pragma unroll 4
    for (int k = 0; k < 96; ++k) {
        float4 w = wp[k];
        float4 v0 = x0[k], v1 = x1[k], v2 = x2[k], v3 = x3[k];
        a0 += w.x * v0.x + w.y * v0.y + w.z * v0.z + w.w * v0.w;
        a1 += w.x * v1.x + w.y * v1.y + w.z * v1.z + w.w * v1.w;
        a2 += w.x * v2.x + w.y * v2.y + w.z * v2.z + w.w * v2.w;
        a3 += w.x * v3.x + w.y * v3.y + w.z * v3.z + w.w * v3.w;
    }
    float bb = bv[j];
    int orow = r0 + rg * 4;
    float acc[4] = {a0, a1, a2, a3};
#pragma unroll
    for (int i = 0; i < 4; ++i)
        val[(size_t)(orow + i) * 384 + j] = acc[i] + bb * ws16[rg * 4 + i];
}

extern "C" void kernel_launch(void* const* d_in, const int* in_sizes, int n_in,
                              void* d_out, int out_size, void* d_ws, size_t ws_size,
                              hipStream_t stream) {
    const float* tgt   = (const float*)d_in[0];
    const float* refp  = (const float*)d_in[1];
    const float* src   = (const float*)d_in[2];
    const float* extra = (const float*)d_in[3];
    const float* vr    = (const float*)d_in[4];
    const float* sa_in_w  = (const float*)d_in[7];
    const float* sa_out_w = (const float*)d_in[8];
    const float* ea_in_w  = (const float*)d_in[9];
    const float* ea_out_w = (const float*)d_in[10];
    const float* ms_off_w = (const float*)d_in[11];
    const float* ms_attn_w= (const float*)d_in[12];
    const float* ms_val_w = (const float*)d_in[13];
    const float* ms_out_w = (const float*)d_in[14];
    const float* ffn_w1   = (const float*)d_in[15];
    const float* ffn_w2   = (const float*)d_in[16];
    const float* sa_in_b  = (const float*)d_in[17];
    const float* sa_out_b = (const float*)d_in[18];
    const float* ea_in_b  = (const float*)d_in[19];
    const float* ea_out_b = (const float*)d_in[20];
    const float* ms_attn_b= (const float*)d_in[21];
    const float* ms_val_b = (const float*)d_in[22];
    const float* ms_out_b = (const float*)d_in[23];
    const float* ffn_b1   = (const float*)d_in[24];
    const float* ffn_b2   = (const float*)d_in[25];
    const float* ln2_b    = (const float*)d_in[26];
    const float* lne_b    = (const float*)d_in[27];
    const float* ln1_b    = (const float*)d_in[28];
    const float* ln3_b    = (const float*)d_in[29];
    const float* ms_off_b = (const float*)d_in[30];
    const float* ln2_g    = (const float*)d_in[31];
    const float* lne_g    = (const float*)d_in[32];
    const float* ln1_g    = (const float*)d_in[33];
    const float* ln3_g    = (const float*)d_in[34];

    float* ws = (float*)d_ws;
    float* s_qkv  = ws;                    // 294912
    float* s_eakv = ws + 294912;           // 393216
    float* s_osa  = ws + 688128;           // 98304
    float* s_z    = ws + 786432;           // 98304 (reused pre-LN buffer)
    float* s_t1   = ws + 884736;           // 98304
    float* s_eaq  = ws + 983040;           // 98304
    float* s_oea  = ws + 1081344;          // 98304
    float* s_t2   = ws + 1179648;          // 98304
    float* s_off  = ws + 1277952;          // 61440
    float* s_lg   = ws + 1339392;          // 30720
    float* s_pagg = ws + 1370112;          // 2949120
    float* s_pws  = ws + 4319232;          // 7680
    float* s_val  = ws + 4326912;          // 98304
    float* s_t3   = ws + 4425216;          // 98304
    float* s_h1   = ws + 4523520;          // 262144

    const size_t LDS384 = 16 * 384 * 4;   // 24 KiB
    const size_t LDS1024 = 16 * 1024 * 4; // 64 KiB

    // 1. SA qkv projection (256 x 1152)
    lin16_kernel<<<dim3(18, 16), 256, LDS384, stream>>>(tgt, sa_in_w, sa_in_b, nullptr, s_qkv, 384, 1152, 0);
    // 2. EA kv projection (512 x 768)
    lin16_kernel<<<dim3(12, 32), 256, LDS384, stream>>>(extra, ea_in_w + (size_t)C_ * C_, ea_in_b + C_, nullptr, s_eakv, 384, 768, 0);
    // 3. self attention
    sa_attn_kernel<<<dim3(256), dim3(384), 0, stream>>>(s_qkv, s_osa);
    // 4. SA out projection + residual(tgt)
    lin16_kernel<<<dim3(6, 16), 256, LDS384, stream>>>(s_osa, sa_out_w, sa_out_b, tgt, s_z, 384, 384, FLAG_RES);
    // 5. LN -> t1
    ln_kernel<<<dim3(256), dim3(64), 0, stream>>>(s_z, ln2_g, ln2_b, s_t1);
    // 6. EA q projection
    lin16_kernel<<<dim3(6, 16), 256, LDS384, stream>>>(s_t1, ea_in_w, ea_in_b, nullptr, s_eaq, 384, 384, 0);
    // 7. cross attention
    ea_attn_kernel<<<dim3(256), dim3(384), 0, stream>>>(s_eaq, s_eakv, s_oea);
    // 8. EA out projection + residual(t1)
    lin16_kernel<<<dim3(6, 16), 256, LDS384, stream>>>(s_oea, ea_out_w, ea_out_b, s_t1, s_z, 384, 384, FLAG_RES);
    // 9. LN -> t2
    ln_kernel<<<dim3(256), dim3(64), 0, stream>>>(s_z, lne_g, lne_b, s_t2);
    // 10. offsets + logits
    prep_kernel<<<dim3(6, 16), 256, LDS384, stream>>>(s_t2, ms_off_w, ms_off_b, ms_attn_w, ms_attn_b, s_off, s_lg);
    // 11. deformable gather (softmax computed locally from logits)
    ms_gather_kernel<<<dim3(5, 6, 256), dim3(128), 0, stream>>>(src, refp, vr, s_off, s_lg, s_pagg, s_pws);
    // 12. level-reduce + value projection
    valproj_kernel<<<dim3(6, 16), 256, 0, stream>>>(s_pagg, s_pws, ms_val_w, ms_val_b, s_val);
    // 13. MS out projection + residual(t2)
    lin16_kernel<<<dim3(6, 16), 256, LDS384, stream>>>(s_val, ms_out_w, ms_out_b, s_t2, s_z, 384, 384, FLAG_RES);
    // 14. LN -> t3
    ln_kernel<<<dim3(256), dim3(64), 0, stream>>>(s_z, ln1_g, ln1_b, s_t3);
    // 15. FFN layer 1 (relu)
    lin16_kernel<<<dim3(16, 16), 256, LDS384, stream>>>(s_t3, ffn_w1, ffn_b1, nullptr, s_h1, 384, 1024, FLAG_RELU);
    // 16. FFN layer 2 + residual(t3)
    lin16_kernel<<<dim3(6, 16), 256, LDS1024, stream>>>(s_h1, ffn_w2, ffn_b2, s_t3, s_z, 1024, 384, FLAG_RES);
    // 17. LN -> out
    ln_kernel<<<dim3(256), dim3(64), 0, stream>>>(s_z, ln3_g, ln3_b, (float*)d_out);
}

// Round 4
// 268.221 us; speedup vs baseline: 1.1054x; 1.1054x over previous
//
#include <hip/hip_runtime.h>
#include <hip/hip_bf16.h>

#define B_ 4
#define Q_ 64
#define C_ 384
#define H_ 6
#define L_ 5
#define P_ 4
#define DFF_ 1024
#define EXTRA_ 128
#define DH_ 64
#define S_ 66836

#define FLAG_RELU 1
#define FLAG_RES 2

__device__ __forceinline__ float wave_sum(float v) {
    for (int off = 32; off; off >>= 1) v += __shfl_xor(v, off);
    return v;
}
__device__ __forceinline__ float wave_max(float v) {
    for (int off = 32; off; off >>= 1) v = fmaxf(v, __shfl_xor(v, off));
    return v;
}
__device__ __forceinline__ float block_sum6(float v, float* red, int t) {
    v = wave_sum(v);
    if ((t & 63) == 0) red[t >> 6] = v;
    __syncthreads();
    float s = red[0] + red[1] + red[2] + red[3] + red[4] + red[5];
    __syncthreads();
    return s;
}

// ---------- combined input projections: qkv (256x1152) + ea kv (512x768) ----------
// grid: 288 + 384 = 672 blocks, 256 threads
__global__ __launch_bounds__(256) void proj_kernel(
        const float* __restrict__ tgt, const float* __restrict__ extra,
        const float* __restrict__ Wqkv, const float* __restrict__ bqkv,
        const float* __restrict__ Wkv, const float* __restrict__ bkv,
        float* __restrict__ qkv, float* __restrict__ eakv) {
    __shared__ float xs[16 * 384];
    int t = threadIdx.x;
    int bx = blockIdx.x;
    const float *in, *W, *bias;
    float* out;
    int OUT, r0, xt;
    if (bx < 288) { xt = bx % 18; r0 = (bx / 18) * 16; in = tgt;   W = Wqkv; bias = bqkv; out = qkv;  OUT = 1152; }
    else { int b2 = bx - 288; xt = b2 % 12; r0 = (b2 / 12) * 16; in = extra; W = Wkv;  bias = bkv;  out = eakv; OUT = 768; }
    const float4* in4 = reinterpret_cast<const float4*>(in + (size_t)r0 * 384);
    float4* xs4 = reinterpret_cast<float4*>(xs);
    for (int i = t; i < 16 * 96; i += 256) xs4[i] = in4[i];
    __syncthreads();
    int j = xt * 64 + (t & 63);
    int rg = t >> 6;
    const float4* wp = reinterpret_cast<const float4*>(W + (size_t)j * 384);
    const float4* x0 = reinterpret_cast<const float4*>(xs + (rg * 4 + 0) * 384);
    const float4* x1 = reinterpret_cast<const float4*>(xs + (rg * 4 + 1) * 384);
    const float4* x2 = reinterpret_cast<const float4*>(xs + (rg * 4 + 2) * 384);
    const float4* x3 = reinterpret_cast<const float4*>(xs + (rg * 4 + 3) * 384);
    float a0 = 0.f, a1 = 0.f, a2 = 0.f, a3 = 0.f;
#pragma unroll 4
    for (int k = 0; k < 96; ++k) {
        float4 w = wp[k];
        float4 v0 = x0[k], v1 = x1[k], v2 = x2[k], v3 = x3[k];
        a0 += w.x * v0.x + w.y * v0.y + w.z * v0.z + w.w * v0.w;
        a1 += w.x * v1.x + w.y * v1.y + w.z * v1.z + w.w * v1.w;
        a2 += w.x * v2.x + w.y * v2.y + w.z * v2.z + w.w * v2.w;
        a3 += w.x * v3.x + w.y * v3.y + w.z * v3.z + w.w * v3.w;
    }
    float bb = bias[j];
    float v[4] = {a0 + bb, a1 + bb, a2 + bb, a3 + bb};
    int orow = r0 + rg * 4;
#pragma unroll
    for (int i = 0; i < 4; ++i) out[(size_t)(orow + i) * OUT + j] = v[i];
}

// ---------- fused self-attention + out-proj + residual + LN (one block per row) ----------
__global__ __launch_bounds__(384) void sa_fused_kernel(
        const float* __restrict__ qkv, const float* __restrict__ res,
        const float* __restrict__ Wo, const float* __restrict__ bo,
        const float* __restrict__ g, const float* __restrict__ beta,
        float* __restrict__ out) {
    int row = blockIdx.x;
    int b = row >> 6;
    int t = threadIdx.x;
    int h = t >> 6, lane = t & 63;
    __shared__ float q_lds[384], a_lds[384], o_lds[384], red[8];
    q_lds[t] = qkv[(size_t)row * 1152 + t];
    __syncthreads();
    const float* krow = qkv + (size_t)(b * 64 + lane) * 1152 + 384 + h * 64;
    float s = 0.f;
#pragma unroll 8
    for (int d = 0; d < 64; ++d) s += q_lds[h * 64 + d] * krow[d];
    s *= 0.125f;
    float m = wave_max(s);
    float e = __expf(s - m);
    float sum = wave_sum(e);
    a_lds[t] = e / sum;
    __syncthreads();
    float acc = 0.f;
#pragma unroll 4
    for (int k = 0; k < 64; ++k)
        acc += a_lds[h * 64 + k] * qkv[(size_t)(b * 64 + k) * 1152 + 768 + h * 64 + lane];
    o_lds[t] = acc;
    __syncthreads();
    const float* wp = Wo + (size_t)t * 384;
    float v = bo[t] + res[(size_t)row * 384 + t];
#pragma unroll 4
    for (int k = 0; k < 384; k += 4) {
        float4 w = *reinterpret_cast<const float4*>(wp + k);
        v += w.x * o_lds[k] + w.y * o_lds[k + 1] + w.z * o_lds[k + 2] + w.w * o_lds[k + 3];
    }
    float mean = block_sum6(v, red, t) * (1.f / 384.f);
    float d = v - mean;
    float var = block_sum6(d * d, red, t) * (1.f / 384.f);
    out[(size_t)row * 384 + t] = d * rsqrtf(var + 1e-5f) * g[t] + beta[t];
}

// ---------- fused EA: q-proj + cross-attn(128 keys) + out-proj + residual + LN ----------
__global__ __launch_bounds__(384) void ea_fused_kernel(
        const float* __restrict__ t1, const float* __restrict__ kv,
        const float* __restrict__ Wq, const float* __restrict__ bq,
        const float* __restrict__ Wo, const float* __restrict__ bo,
        const float* __restrict__ g, const float* __restrict__ beta,
        float* __restrict__ out) {
    int row = blockIdx.x;
    int b = row >> 6;
    int t = threadIdx.x;
    int h = t >> 6, lane = t & 63;
    __shared__ float in_lds[384], q_lds[384], a_lds[768], o_lds[384], red[8];
    in_lds[t] = t1[(size_t)row * 384 + t];
    __syncthreads();
    const float* wq = Wq + (size_t)t * 384;
    float qv = bq[t];
#pragma unroll 4
    for (int k = 0; k < 384; k += 4) {
        float4 w = *reinterpret_cast<const float4*>(wq + k);
        qv += w.x * in_lds[k] + w.y * in_lds[k + 1] + w.z * in_lds[k + 2] + w.w * in_lds[k + 3];
    }
    q_lds[t] = qv;
    __syncthreads();
    const float* k0 = kv + (size_t)(b * 128 + lane) * 768 + h * 64;
    const float* k1 = k0 + (size_t)64 * 768;
    float s0 = 0.f, s1 = 0.f;
#pragma unroll 8
    for (int d = 0; d < 64; ++d) { float qd = q_lds[h * 64 + d]; s0 += qd * k0[d]; s1 += qd * k1[d]; }
    s0 *= 0.125f; s1 *= 0.125f;
    float m = wave_max(fmaxf(s0, s1));
    float e0 = __expf(s0 - m), e1 = __expf(s1 - m);
    float sum = wave_sum(e0 + e1);
    a_lds[h * 128 + lane] = e0 / sum;
    a_lds[h * 128 + 64 + lane] = e1 / sum;
    __syncthreads();
    float acc = 0.f;
#pragma unroll 4
    for (int k = 0; k < 128; ++k)
        acc += a_lds[h * 128 + k] * kv[(size_t)(b * 128 + k) * 768 + 384 + h * 64 + lane];
    o_lds[t] = acc;
    __syncthreads();
    const float* wo = Wo + (size_t)t * 384;
    float v = bo[t] + in_lds[t];
#pragma unroll 4
    for (int k = 0; k < 384; k += 4) {
        float4 w = *reinterpret_cast<const float4*>(wo + k);
        v += w.x * o_lds[k] + w.y * o_lds[k + 1] + w.z * o_lds[k + 2] + w.w * o_lds[k + 3];
    }
    float mean = block_sum6(v, red, t) * (1.f / 384.f);
    float d = v - mean;
    float var = block_sum6(d * d, red, t) * (1.f / 384.f);
    out[(size_t)row * 384 + t] = d * rsqrtf(var + 1e-5f) * g[t] + beta[t];
}

// ---------- offsets (240) + attn logits (120); tiled over 16 rows ----------
__global__ __launch_bounds__(256) void prep_kernel(
        const float* __restrict__ in, const float* __restrict__ Woff,
        const float* __restrict__ boff, const float* __restrict__ Wa,
        const float* __restrict__ ba, float* __restrict__ offs,
        float* __restrict__ lg) {
    __shared__ float xs[16 * 384];
    int t = threadIdx.x;
    int r0 = blockIdx.y * 16;
    const float4* in4 = reinterpret_cast<const float4*>(in + (size_t)r0 * 384);
    float4* xs4 = reinterpret_cast<float4*>(xs);
    for (int i = t; i < 16 * 96; i += 256) xs4[i] = in4[i];
    __syncthreads();
    int j = blockIdx.x * 64 + (t & 63);
    int rg = t >> 6;
    if (j >= 360) return;
    const float4* wp;
    float bb;
    if (j < 240) { wp = reinterpret_cast<const float4*>(Woff + (size_t)j * 384); bb = boff[j]; }
    else         { wp = reinterpret_cast<const float4*>(Wa + (size_t)(j - 240) * 384); bb = ba[j - 240]; }
    const float4* x0 = reinterpret_cast<const float4*>(xs + (rg * 4 + 0) * 384);
    const float4* x1 = reinterpret_cast<const float4*>(xs + (rg * 4 + 1) * 384);
    const float4* x2 = reinterpret_cast<const float4*>(xs + (rg * 4 + 2) * 384);
    const float4* x3 = reinterpret_cast<const float4*>(xs + (rg * 4 + 3) * 384);
    float a0 = 0.f, a1 = 0.f, a2 = 0.f, a3 = 0.f;
#pragma unroll 4
    for (int k = 0; k < 96; ++k) {
        float4 w = wp[k];
        float4 v0 = x0[k], v1 = x1[k], v2 = x2[k], v3 = x3[k];
        a0 += w.x * v0.x + w.y * v0.y + w.z * v0.z + w.w * v0.w;
        a1 += w.x * v1.x + w.y * v1.y + w.z * v1.z + w.w * v1.w;
        a2 += w.x * v2.x + w.y * v2.y + w.z * v2.z + w.w * v2.w;
        a3 += w.x * v3.x + w.y * v3.y + w.z * v3.z + w.w * v3.w;
    }
    float v[4] = {a0 + bb, a1 + bb, a2 + bb, a3 + bb};
    int orow = r0 + rg * 4;
#pragma unroll
    for (int i = 0; i < 4; ++i) {
        if (j < 240) offs[(size_t)(orow + i) * 240 + j] = v[i];
        else         lg[(size_t)(orow + i) * 120 + (j - 240)] = v[i];
    }
}

// ---------- deformable gather with local softmax; block per (l,h,row) ----------
__global__ __launch_bounds__(128) void ms_gather_kernel(
        const float* __restrict__ src, const float* __restrict__ refp,
        const float* __restrict__ vr, const float* __restrict__ offs,
        const float* __restrict__ lg, float* __restrict__ pagg,
        float* __restrict__ pwsum) {
    int l = blockIdx.x, h = blockIdx.y, row = blockIdx.z;
    int b = row >> 6;
    int t = threadIdx.x;
    const int lsi[5] = {0, 196, 980, 4116, 16660};
    const int whl[5] = {14, 28, 56, 112, 224};
    int wh = whl[l];
    float Wf = (float)wh;
    const float* lp = lg + (size_t)row * 120 + h * 20;
    float m = -1e30f;
#pragma unroll
    for (int k = 0; k < 20; ++k) m = fmaxf(m, lp[k]);
    float denom = 0.f;
#pragma unroll
    for (int k = 0; k < 20; ++k) denom += __expf(lp[k] - m);
    float dinv = 1.f / denom;
    float rpx = refp[row * 2 + 0] * vr[(b * 5 + l) * 2 + 0];
    float rpy = refp[row * 2 + 1] * vr[(b * 5 + l) * 2 + 1];
    const float* srcb = src + ((size_t)b * S_ + lsi[l]) * 384;
    float acc0 = 0.f, acc1 = 0.f, acc2 = 0.f, wsm = 0.f;
#pragma unroll
    for (int p = 0; p < 4; ++p) {
        int oidx = row * 240 + ((h * 5 + l) * 4 + p) * 2;
        float ox = offs[oidx], oy = offs[oidx + 1];
        float x = (rpx + ox / Wf) * Wf - 0.5f;
        float y = (rpy + oy / Wf) * Wf - 0.5f;
        float x0 = floorf(x), y0 = floorf(y);
        float wx = x - x0, wy = y - y0;
        float a = __expf(lp[l * 4 + p] - m) * dinv;
        float cw[4] = {(1.f - wx) * (1.f - wy), wx * (1.f - wy), (1.f - wx) * wy, wx * wy};
        float cx[4] = {x0, x0 + 1.f, x0, x0 + 1.f};
        float cy[4] = {y0, y0, y0 + 1.f, y0 + 1.f};
#pragma unroll
        for (int c2 = 0; c2 < 4; ++c2) {
            bool valid = (cx[c2] >= 0.f) && (cx[c2] <= Wf - 1.f) &&
                         (cy[c2] >= 0.f) && (cy[c2] <= Wf - 1.f);
            if (!valid) continue;
            float w = a * cw[c2];
            wsm += w;
            int xi = (int)cx[c2], yi = (int)cy[c2];
            const float* sp = srcb + (size_t)(yi * wh + xi) * 384;
            acc0 += w * sp[t];
            acc1 += w * sp[t + 128];
            acc2 += w * sp[t + 256];
        }
    }
    float* ap = pagg + ((size_t)(row * 6 + h) * 5 + l) * 384;
    ap[t] = acc0; ap[t + 128] = acc1; ap[t + 256] = acc2;
    if (t == 0) pwsum[(row * 6 + h) * 5 + l] = wsm;
}

// ---------- fused: level-reduce + value-proj + out-proj + residual + LN ----------
__global__ __launch_bounds__(384) void ms_valout_kernel(
        const float* __restrict__ pagg, const float* __restrict__ pwsum,
        const float* __restrict__ Wv, const float* __restrict__ bv,
        const float* __restrict__ Wo, const float* __restrict__ bo,
        const float* __restrict__ t2, const float* __restrict__ g,
        const float* __restrict__ beta, float* __restrict__ out) {
    int row = blockIdx.x;
    int t = threadIdx.x;
    __shared__ float agg[2304], val[384], wsum[6], red[8];
#pragma unroll
    for (int e = 0; e < 6; ++e) {
        int idx = t + e * 384;
        int hh = idx / 384, col = idx % 384;
        const float* pp = pagg + ((size_t)(row * 6 + hh) * 5) * 384 + col;
        agg[idx] = pp[0] + pp[384] + pp[768] + pp[1152] + pp[1536];
    }
    if (t < 6) {
        const float* pw = pwsum + (row * 6 + t) * 5;
        wsum[t] = pw[0] + pw[1] + pw[2] + pw[3] + pw[4];
    }
    __syncthreads();
    int h = t >> 6;
    const float* wp = Wv + (size_t)t * 384;
    const float* ag = agg + h * 384;
    float v = bv[t] * wsum[h];
#pragma unroll 4
    for (int k = 0; k < 384; k += 4) {
        float4 w = *reinterpret_cast<const float4*>(wp + k);
        v += w.x * ag[k] + w.y * ag[k + 1] + w.z * ag[k + 2] + w.w * ag[k + 3];
    }
    val[t] = v;
    __syncthreads();
    const float* wo = Wo + (size_t)t * 384;
    float o = bo[t] + t2[(size_t)row * 384 + t];
#pragma unroll 4
    for (int k = 0; k < 384; k += 4) {
        float4 w = *reinterpret_cast<const float4*>(wo + k);
        o += w.x * val[k] + w.y * val[k + 1] + w.z * val[k + 2] + w.w * val[k + 3];
    }
    float mean = block_sum6(o, red, t) * (1.f / 384.f);
    float d = o - mean;
    float var = block_sum6(d * d, red, t) * (1.f / 384.f);
    out[(size_t)row * 384 + t] = d * rsqrtf(var + 1e-5f) * g[t] + beta[t];
}

// ---------- 16-row-tiled linear (runtime K/OUT, optional res/relu) ----------
__global__ __launch_bounds__(256) void lin16_kernel(
        const float* __restrict__ in, const float* __restrict__ W,
        const float* __restrict__ bias, const float* __restrict__ res,
        float* __restrict__ out, int K, int OUT, int flags) {
    extern __shared__ float xs[];
    int t = threadIdx.x;
    int r0 = blockIdx.y * 16;
    int K4 = K >> 2;
    const float4* in4 = reinterpret_cast<const float4*>(in + (size_t)r0 * K);
    float4* xs4 = reinterpret_cast<float4*>(xs);
    for (int i = t; i < 16 * K4; i += 256) xs4[i] = in4[i];
    __syncthreads();
    int j = blockIdx.x * 64 + (t & 63);
    int rg = t >> 6;
    if (j >= OUT) return;
    const float4* wp = reinterpret_cast<const float4*>(W + (size_t)j * K);
    const float4* x0 = reinterpret_cast<const float4*>(xs + (rg * 4 + 0) * K);
    const float4* x1 = reinterpret_cast<const float4*>(xs + (rg * 4 + 1) * K);
    const float4* x2 = reinterpret_cast<const float4*>(xs + (rg * 4 + 2) * K);
    const float4* x3 = reinterpret_cast<const float4*>(xs + (rg * 4 + 3) * K);
    float a0 = 0.f, a1 = 0.f, a2 = 0.f, a3 = 0.f;
#pragma unroll 4
    for (int k = 0; k < K4; ++k) {
        float4 w = wp[k];
        float4 v0 = x0[k], v1 = x1[k], v2 = x2[k], v3 = x3[k];
        a0 += w.x * v0.x + w.y * v0.y + w.z * v0.z + w.w * v0.w;
        a1 += w.x * v1.x + w.y * v1.y + w.z * v1.z + w.w * v1.w;
        a2 += w.x * v2.x + w.y * v2.y + w.z * v2.z + w.w * v2.w;
        a3 += w.x * v3.x + w.y * v3.y + w.z * v3.z + w.w * v3.w;
    }
    float bb = bias[j];
    float v[4] = {a0 + bb, a1 + bb, a2 + bb, a3 + bb};
    int orow = r0 + rg * 4;
#pragma unroll
    for (int i = 0; i < 4; ++i) {
        float o = v[i];
        if (flags & FLAG_RES) o += res[(size_t)(orow + i) * OUT + j];
        if (flags & FLAG_RELU) o = fmaxf(o, 0.f);
        out[(size_t)(orow + i) * OUT + j] = o;
    }
}

// ---------- LayerNorm, one wave per row ----------
__global__ __launch_bounds__(64) void ln_kernel(const float* __restrict__ z,
                                                const float* __restrict__ g,
                                                const float* __restrict__ beta,
                                                float* __restrict__ out) {
    int row = blockIdx.x;
    int t = threadIdx.x;
    float v[6];
    float mean = 0.f;
#pragma unroll
    for (int i = 0; i < 6; ++i) {
        v[i] = z[(size_t)row * C_ + t + i * 64];
        mean += v[i];
    }
    mean = wave_sum(mean) * (1.f / C_);
    float var = 0.f;
#pragma unroll
    for (int i = 0; i < 6; ++i) { float d = v[i] - mean; var += d * d; }
    var = wave_sum(var) * (1.f / C_);
    float inv = rsqrtf(var + 1e-5f);
#pragma unroll
    for (int i = 0; i < 6; ++i) {
        int c = t + i * 64;
        out[(size_t)row * C_ + c] = (v[i] - mean) * inv * g[c] + beta[c];
    }
}

extern "C" void kernel_launch(void* const* d_in, const int* in_sizes, int n_in,
                              void* d_out, int out_size, void* d_ws, size_t ws_size,
                              hipStream_t stream) {
    const float* tgt   = (const float*)d_in[0];
    const float* refp  = (const float*)d_in[1];
    const float* src   = (const float*)d_in[2];
    const float* extra = (const float*)d_in[3];
    const float* vr    = (const float*)d_in[4];
    const float* sa_in_w  = (const float*)d_in[7];
    const float* sa_out_w = (const float*)d_in[8];
    const float* ea_in_w  = (const float*)d_in[9];
    const float* ea_out_w = (const float*)d_in[10];
    const float* ms_off_w = (const float*)d_in[11];
    const float* ms_attn_w= (const float*)d_in[12];
    const float* ms_val_w = (const float*)d_in[13];
    const float* ms_out_w = (const float*)d_in[14];
    const float* ffn_w1   = (const float*)d_in[15];
    const float* ffn_w2   = (const float*)d_in[16];
    const float* sa_in_b  = (const float*)d_in[17];
    const float* sa_out_b = (const float*)d_in[18];
    const float* ea_in_b  = (const float*)d_in[19];
    const float* ea_out_b = (const float*)d_in[20];
    const float* ms_attn_b= (const float*)d_in[21];
    const float* ms_val_b = (const float*)d_in[22];
    const float* ms_out_b = (const float*)d_in[23];
    const float* ffn_b1   = (const float*)d_in[24];
    const float* ffn_b2   = (const float*)d_in[25];
    const float* ln2_b    = (const float*)d_in[26];
    const float* lne_b    = (const float*)d_in[27];
    const float* ln1_b    = (const float*)d_in[28];
    const float* ln3_b    = (const float*)d_in[29];
    const float* ms_off_b = (const float*)d_in[30];
    const float* ln2_g    = (const float*)d_in[31];
    const float* lne_g    = (const float*)d_in[32];
    const float* ln1_g    = (const float*)d_in[33];
    const float* ln3_g    = (const float*)d_in[34];

    float* ws = (float*)d_ws;
    float* s_qkv  = ws;                    // 294912
    float* s_eakv = ws + 294912;           // 393216
    float* s_t1   = ws + 688128;           // 98304
    float* s_t2   = ws + 786432;           // 98304
    float* s_off  = ws + 884736;           // 61440
    float* s_lg   = ws + 946176;           // 30720
    float* s_pagg = ws + 976896;           // 2949120
    float* s_pws  = ws + 3926016;          // 7680
    float* s_t3   = ws + 3933696;          // 98304
    float* s_h1   = ws + 4032000;          // 262144
    float* s_z    = ws + 4294144;          // 98304

    const size_t LDS384 = 16 * 384 * 4;
    const size_t LDS1024 = 16 * 1024 * 4;

    // 1. combined qkv + ea kv projections
    proj_kernel<<<dim3(672), dim3(256), 0, stream>>>(tgt, extra, sa_in_w, sa_in_b,
        ea_in_w + (size_t)C_ * C_, ea_in_b + C_, s_qkv, s_eakv);
    // 2. fused SA (attn + out-proj + res + LN) -> t1
    sa_fused_kernel<<<dim3(256), dim3(384), 0, stream>>>(s_qkv, tgt, sa_out_w, sa_out_b, ln2_g, ln2_b, s_t1);
    // 3. fused EA (q-proj + attn + out-proj + res + LN) -> t2
    ea_fused_kernel<<<dim3(256), dim3(384), 0, stream>>>(s_t1, s_eakv, ea_in_w, ea_in_b, ea_out_w, ea_out_b, lne_g, lne_b, s_t2);
    // 4. offsets + logits
    prep_kernel<<<dim3(6, 16), dim3(256), 0, stream>>>(s_t2, ms_off_w, ms_off_b, ms_attn_w, ms_attn_b, s_off, s_lg);
    // 5. deformable gather
    ms_gather_kernel<<<dim3(5, 6, 256), dim3(128), 0, stream>>>(src, refp, vr, s_off, s_lg, s_pagg, s_pws);
    // 6. fused level-reduce + val-proj + out-proj + res + LN -> t3
    ms_valout_kernel<<<dim3(256), dim3(384), 0, stream>>>(s_pagg, s_pws, ms_val_w, ms_val_b, ms_out_w, ms_out_b, s_t2, ln1_g, ln1_b, s_t3);
    // 7. FFN1 (relu)
    lin16_kernel<<<dim3(16, 16), dim3(256), LDS384, stream>>>(s_t3, ffn_w1, ffn_b1, nullptr, s_h1, 384, 1024, FLAG_RELU);
    // 8. FFN2 + res(t3)
    lin16_kernel<<<dim3(6, 16), dim3(256), LDS1024, stream>>>(s_h1, ffn_w2, ffn_b2, s_t3, s_z, 1024, 384, FLAG_RES);
    // 9. final LN -> out
    ln_kernel<<<dim3(256), dim3(64), 0, stream>>>(s_z, ln3_g, ln3_b, (float*)d_out);
}